// Round 6
// baseline (121.446 us; speedup 1.0000x reference)
//
#include <hip/hip_runtime.h>
#include <hip/hip_cooperative_groups.h>
#include <math.h>

namespace cg = cooperative_groups;

#define BATCH 16
#define N_ROIS 1000
#define NUM_CLASSES 81
#define DET_MAX 100
#define MIN_CONF 0.7f
#define NMS_THRESH 0.3f

#define ROI_TILE 128
#define N_TILES 125            // 16000 / 128
#define GRID 128               // 125 refine blocks + 3 idle; blocks 0..15 do NMS

// LDS is time-shared between the two phases (grid.sync separates them).
union SMem {
    float tile[ROI_TILE * NUM_CLASSES];       // 40.5 KB (phase 1)
    struct {                                  // ~47.7 KB (phase 2)
        float cbox[N_ROIS][4];                // candidates (compaction order)
        float sbox[N_ROIS][4];                // sorted by (score desc, idx asc)
        float csc[N_ROIS];
        float ssc[N_ROIS];
        short cidx[N_ROIS];                   // original roi idx (tie-break)
        short bucket[N_ROIS];                 // per-class lists of sorted idx
        unsigned char ccls[N_ROIS];
        unsigned char scls[N_ROIS];
        unsigned char kept[N_ROIS];
        int cnt[NUM_CLASSES];
        int off[NUM_CLASSES];
        int C;
    } n;
};

// Fused: phase 1 = refine_v4 semantics at full 125-block parallelism;
// grid.sync() (device-scope visibility for the ws handoff across XCDs);
// phase 2 = nms_v4 semantics, blocks 0..15 (one per batch).
__global__ __launch_bounds__(256) void detect_coop(
    const float* __restrict__ rois, const float* __restrict__ probs,
    const float* __restrict__ deltas, const float* __restrict__ window,
    float* __restrict__ ws_box, float* __restrict__ ws_score,
    int* __restrict__ ws_cls, float* __restrict__ out)
{
    __shared__ SMem sm;
    const int tid = threadIdx.x;
    const int blk = blockIdx.x;

    // ---------------- Phase 1: per-ROI argmax + refine + clip ----------------
    if (blk < N_TILES) {
        const int base_roi = blk * ROI_TILE;

        // coalesced float4 staging: 128*81/4 = 2592 float4 (base 16B-aligned)
        const float4* src = (const float4*)(probs + (size_t)base_roi * NUM_CLASSES);
        float4* dst = (float4*)sm.tile;
        for (int i = tid; i < ROI_TILE * NUM_CLASSES / 4; i += 256)
            dst[i] = src[i];
        __syncthreads();

        if (tid < ROI_TILE) {
            const int idx = base_roi + tid;        // flat ROI id, < 16000
            const int b = idx / N_ROIS;

            // 4-chain argmax (dep depth 80 -> ~20); merges keep lowest-index
            // maximum => identical to jnp.argmax first-max-wins.
            const float* p = sm.tile + tid * NUM_CLASSES;
            float bs0 = p[0], bs1 = p[1], bs2 = p[2], bs3 = p[3];
            int ib0 = 0, ib1 = 1, ib2 = 2, ib3 = 3;
            #pragma unroll
            for (int c = 4; c <= 76; c += 4) {
                float v0 = p[c], v1 = p[c + 1], v2 = p[c + 2], v3 = p[c + 3];
                if (v0 > bs0) { bs0 = v0; ib0 = c; }
                if (v1 > bs1) { bs1 = v1; ib1 = c + 1; }
                if (v2 > bs2) { bs2 = v2; ib2 = c + 2; }
                if (v3 > bs3) { bs3 = v3; ib3 = c + 3; }
            }
            { float v = p[80]; if (v > bs0) { bs0 = v; ib0 = 80; } }
            if (bs1 > bs0 || (bs1 == bs0 && ib1 < ib0)) { bs0 = bs1; ib0 = ib1; }
            if (bs3 > bs2 || (bs3 == bs2 && ib3 < ib2)) { bs2 = bs3; ib2 = ib3; }
            if (bs2 > bs0 || (bs2 == bs0 && ib2 < ib0)) { bs0 = bs2; ib0 = ib2; }
            const float bs = bs0;
            const int best = ib0;

            const bool keep = (best > 0) && (bs >= MIN_CONF);
            ws_score[idx] = keep ? bs : -1.0f;

            if (keep) {
                const float4 dd = ((const float4*)deltas)[(size_t)idx * NUM_CLASSES + best];
                float dy = dd.x * 0.1f, dx = dd.y * 0.1f, dh = dd.z * 0.2f, dw = dd.w * 0.2f;

                const float4 rr = ((const float4*)rois)[idx];
                float y1 = rr.x, x1 = rr.y, y2 = rr.z, x2 = rr.w;
                float h = y2 - y1, w = x2 - x1;
                float cy = y1 + 0.5f * h, cx = x1 + 0.5f * w;
                cy += dy * h;
                cx += dx * w;
                h *= expf(dh);
                w *= expf(dw);
                float ny1 = cy - 0.5f * h;
                float nx1 = cx - 0.5f * w;
                float ny2 = ny1 + h;   // matches reference: y2 = y1 + h
                float nx2 = nx1 + w;

                const float* win = window + b * 4;
                float wy1 = win[0], wx1 = win[1], wy2 = win[2], wx2 = win[3];
                ny1 = fminf(fmaxf(ny1, wy1), wy2);
                nx1 = fminf(fmaxf(nx1, wx1), wx2);
                ny2 = fminf(fmaxf(ny2, wy1), wy2);
                nx2 = fminf(fmaxf(nx2, wx1), wx2);

                ((float4*)ws_box)[idx] = make_float4(ny1, nx1, ny2, nx2);
                ws_cls[idx] = best;
            }
        }
    }
    // zero output rows (d_out poisoned before every replay); phase 2 only
    // writes kept slots, so this must complete before phase 2 (grid.sync).
    if (blk < BATCH) {
        for (int i = tid; i < DET_MAX * 6; i += 256)
            out[(size_t)blk * DET_MAX * 6 + i] = 0.0f;
    }

    cg::this_grid().sync();

    // ---------------- Phase 2: per-batch sort + per-class NMS + top-K --------
    if (blk >= BATCH) return;
    const int b = blk;

    if (tid == 0) sm.n.C = 0;
    if (tid < NUM_CLASSES) sm.n.cnt[tid] = 0;
    __syncthreads();

    // compact candidates (score >= 0) into LDS
    for (int i = tid; i < N_ROIS; i += 256) {
        float sc = ws_score[b * N_ROIS + i];
        if (sc >= 0.0f) {
            int k = atomicAdd(&sm.n.C, 1);
            sm.n.csc[k] = sc;
            sm.n.cidx[k] = (short)i;
            int c = ws_cls[b * N_ROIS + i];
            sm.n.ccls[k] = (unsigned char)c;
            atomicAdd(&sm.n.cnt[c], 1);
            float4 bb = ((const float4*)ws_box)[b * N_ROIS + i];
            sm.n.cbox[k][0] = bb.x; sm.n.cbox[k][1] = bb.y;
            sm.n.cbox[k][2] = bb.z; sm.n.cbox[k][3] = bb.w;
        }
    }
    __syncthreads();
    const int C = sm.n.C;

    if (tid == 0) {
        int acc = 0;
        for (int c = 0; c < NUM_CLASSES; ++c) { sm.n.off[c] = acc; acc += sm.n.cnt[c]; }
    }
    __syncthreads();

    // rank-sort by (score desc, idx asc) + direct class-bucket scatter
    for (int k = tid; k < C; k += 256) {
        float sk = sm.n.csc[k];
        int ik = sm.n.cidx[k];
        int ck = sm.n.ccls[k];
        int rank = 0, crank = 0;
        for (int j = 0; j < C; ++j) {   // broadcast LDS reads
            float sj = sm.n.csc[j];
            int before = (sj > sk) | ((sj == sk) & (sm.n.cidx[j] < ik));
            rank += before;
            crank += before & (sm.n.ccls[j] == ck);
        }
        sm.n.ssc[rank] = sk;
        sm.n.scls[rank] = (unsigned char)ck;
        sm.n.sbox[rank][0] = sm.n.cbox[k][0];
        sm.n.sbox[rank][1] = sm.n.cbox[k][1];
        sm.n.sbox[rank][2] = sm.n.cbox[k][2];
        sm.n.sbox[rank][3] = sm.n.cbox[k][3];
        sm.n.kept[rank] = 0;
        sm.n.bucket[sm.n.off[ck] + crank] = (short)rank;
    }
    __syncthreads();

    // per-class greedy NMS, all classes in parallel: kept iff not suppressed
    // (IoU > thresh) by an earlier KEPT same-class box; DET_MAX cap.
    if (tid >= 1 && tid < NUM_CLASSES) {
        const int off = sm.n.off[tid];
        const int m = sm.n.cnt[tid];
        int kept_cnt = 0;
        for (int a = 0; a < m; ++a) {
            if (kept_cnt >= DET_MAX) break;
            int i = sm.n.bucket[off + a];
            float b0 = sm.n.sbox[i][0], b1 = sm.n.sbox[i][1];
            float b2 = sm.n.sbox[i][2], b3 = sm.n.sbox[i][3];
            float area_b = (b2 - b0) * (b3 - b1);
            bool sup = false;
            for (int q = 0; q < a; ++q) {
                int j = sm.n.bucket[off + q];
                if (!sm.n.kept[j]) continue;
                float a0 = sm.n.sbox[j][0], a1 = sm.n.sbox[j][1];
                float a2 = sm.n.sbox[j][2], a3 = sm.n.sbox[j][3];
                float yy1 = fmaxf(a0, b0);
                float xx1 = fmaxf(a1, b1);
                float yy2 = fminf(a2, b2);
                float xx2 = fminf(a3, b3);
                float inter = fmaxf(yy2 - yy1, 0.0f) * fmaxf(xx2 - xx1, 0.0f);
                float area_a = (a2 - a0) * (a3 - a1);
                float uni = area_a + area_b - inter;
                if (inter / fmaxf(uni, 1e-10f) > NMS_THRESH) { sup = true; break; }
            }
            if (!sup) { sm.n.kept[i] = 1; ++kept_cnt; }
        }
    }
    __syncthreads();

    // emit: slot = prefix count of kept in sorted order (== lax.top_k order)
    for (int i = tid; i < C; i += 256) {
        if (sm.n.kept[i]) {
            int slot = 0;
            for (int j = 0; j < i; ++j) slot += sm.n.kept[j];
            if (slot < DET_MAX) {
                float* o = out + (size_t)b * DET_MAX * 6 + slot * 6;
                o[0] = sm.n.sbox[i][0];
                o[1] = sm.n.sbox[i][1];
                o[2] = sm.n.sbox[i][2];
                o[3] = sm.n.sbox[i][3];
                o[4] = (float)sm.n.scls[i];
                o[5] = sm.n.ssc[i];
            }
        }
    }
}

extern "C" void kernel_launch(void* const* d_in, const int* in_sizes, int n_in,
                              void* d_out, int out_size, void* d_ws, size_t ws_size,
                              hipStream_t stream) {
    const float* rois      = (const float*)d_in[0];
    const float* fpn_class = (const float*)d_in[1];
    const float* fpn_bbox  = (const float*)d_in[2];
    const float* window    = (const float*)d_in[3];
    float* out = (float*)d_out;

    // workspace layout: boxes | scores | class ids  (384 KB of d_ws)
    float* ws_box   = (float*)d_ws;                        // BATCH*N_ROIS*4
    float* ws_score = ws_box + (size_t)BATCH * N_ROIS * 4; // BATCH*N_ROIS
    int*   ws_cls   = (int*)(ws_score + (size_t)BATCH * N_ROIS);

    void* args[] = { (void*)&rois, (void*)&fpn_class, (void*)&fpn_bbox, (void*)&window,
                     (void*)&ws_box, (void*)&ws_score, (void*)&ws_cls, (void*)&out };
    hipLaunchCooperativeKernel((const void*)detect_coop, dim3(GRID), dim3(256),
                               args, 0, stream);
}

// Round 7
// 85.800 us; speedup vs baseline: 1.4155x; 1.4155x over previous
//
#include <hip/hip_runtime.h>
#include <math.h>

#define BATCH 16
#define N_ROIS 1000
#define NUM_CLASSES 81
#define DET_MAX 100
#define MIN_CONF 0.7f
#define NMS_THRESH 0.3f

#define ROI_TILE 128          // ROIs per block in refine kernel

// ---------------- Kernel A: per-ROI argmax + box refine + clip ----------------
// 125 blocks. Argmax done as 4 independent chains (dep depth 80 -> ~20) merged
// with index tie-breaks: picks the lowest-index maximum == jnp.argmax.
// NOTE (R6 lesson): do NOT fuse with kernel B — grid.sync() on gfx950 costs
// ~35 us (cross-XCD barrier), vs ~2-3 us for a second graph-replayed dispatch.
__global__ __launch_bounds__(256) void refine_v4(
    const float* __restrict__ rois, const float* __restrict__ probs,
    const float* __restrict__ deltas, const float* __restrict__ window,
    float* __restrict__ ws_box, float* __restrict__ ws_score, int* __restrict__ ws_cls)
{
    __shared__ float s_probs[ROI_TILE * NUM_CLASSES];   // 40.5 KB

    const int base_roi = blockIdx.x * ROI_TILE;

    // coalesced float4 staging: 128*81/4 = 2592 float4 (base 16B-aligned)
    const float4* src = (const float4*)(probs + (size_t)base_roi * NUM_CLASSES);
    float4* dst = (float4*)s_probs;
    for (int i = threadIdx.x; i < ROI_TILE * NUM_CLASSES / 4; i += 256)
        dst[i] = src[i];
    __syncthreads();

    if (threadIdx.x < ROI_TILE) {
        const int idx = base_roi + threadIdx.x;   // flat ROI id, < 16000
        const int b = idx / N_ROIS;

        // 4-chain argmax over 81 probs; within-chain: strict > keeps first max;
        // cross-chain merge keeps lowest-index maximum => jnp.argmax semantics.
        const float* p = s_probs + threadIdx.x * NUM_CLASSES;
        float bs0 = p[0], bs1 = p[1], bs2 = p[2], bs3 = p[3];
        int ib0 = 0, ib1 = 1, ib2 = 2, ib3 = 3;
        #pragma unroll
        for (int c = 4; c <= 76; c += 4) {
            float v0 = p[c], v1 = p[c + 1], v2 = p[c + 2], v3 = p[c + 3];
            if (v0 > bs0) { bs0 = v0; ib0 = c; }
            if (v1 > bs1) { bs1 = v1; ib1 = c + 1; }
            if (v2 > bs2) { bs2 = v2; ib2 = c + 2; }
            if (v3 > bs3) { bs3 = v3; ib3 = c + 3; }
        }
        { float v = p[80]; if (v > bs0) { bs0 = v; ib0 = 80; } }
        if (bs1 > bs0 || (bs1 == bs0 && ib1 < ib0)) { bs0 = bs1; ib0 = ib1; }
        if (bs3 > bs2 || (bs3 == bs2 && ib3 < ib2)) { bs2 = bs3; ib2 = ib3; }
        if (bs2 > bs0 || (bs2 == bs0 && ib2 < ib0)) { bs0 = bs2; ib0 = ib2; }
        const float bs = bs0;
        const int best = ib0;

        const bool keep = (best > 0) && (bs >= MIN_CONF);
        ws_score[idx] = keep ? bs : -1.0f;

        if (keep) {
            const float4 dd = ((const float4*)deltas)[(size_t)idx * NUM_CLASSES + best];
            float dy = dd.x * 0.1f, dx = dd.y * 0.1f, dh = dd.z * 0.2f, dw = dd.w * 0.2f;

            const float4 rr = ((const float4*)rois)[idx];
            float y1 = rr.x, x1 = rr.y, y2 = rr.z, x2 = rr.w;
            float h = y2 - y1, w = x2 - x1;
            float cy = y1 + 0.5f * h, cx = x1 + 0.5f * w;
            cy += dy * h;
            cx += dx * w;
            h *= expf(dh);
            w *= expf(dw);
            float ny1 = cy - 0.5f * h;
            float nx1 = cx - 0.5f * w;
            float ny2 = ny1 + h;   // matches reference: y2 = y1 + h
            float nx2 = nx1 + w;

            const float* win = window + b * 4;
            float wy1 = win[0], wx1 = win[1], wy2 = win[2], wx2 = win[3];
            ny1 = fminf(fmaxf(ny1, wy1), wy2);
            nx1 = fminf(fmaxf(nx1, wx1), wx2);
            ny2 = fminf(fmaxf(ny2, wy1), wy2);
            nx2 = fminf(fmaxf(nx2, wx1), wx2);

            ((float4*)ws_box)[idx] = make_float4(ny1, nx1, ny2, nx2);
            ws_cls[idx] = best;
        }
    }
}

// ---------------- Kernel B: per-batch sort + per-class parallel NMS + top-K ----
// Equivalence to the reference:
//  - global rank-sort by (score desc, roi-idx asc) preserves each class's
//    stable argsort(-sc) order; per-class greedy NMS over the class bucket is
//    exactly the reference recursion (kept iff not suppressed by an earlier
//    KEPT same-class box; DET_MAX cap => capped boxes neither keep/suppress).
//  - kept subset in global sorted order == lax.top_k order of sf;
//    slot = prefix count of kept flags; rows beyond kept count stay zero.
__global__ __launch_bounds__(256) void nms_v4(
    const float* __restrict__ ws_box, const float* __restrict__ ws_score,
    const int* __restrict__ ws_cls, float* __restrict__ out)
{
    const int b = blockIdx.x;
    const int tid = threadIdx.x;

    __shared__ float s_cbox[N_ROIS][4];        // candidates (compaction order)
    __shared__ float s_csc[N_ROIS];
    __shared__ short s_cidx[N_ROIS];           // original roi idx (tie-break)
    __shared__ unsigned char s_ccls[N_ROIS];
    __shared__ float s_sbox[N_ROIS][4];        // sorted by (score desc, idx asc)
    __shared__ float s_ssc[N_ROIS];
    __shared__ unsigned char s_scls[N_ROIS];
    __shared__ unsigned char s_kept[N_ROIS];
    __shared__ short s_bucket[N_ROIS];         // per-class lists of sorted idx
    __shared__ int s_cnt[NUM_CLASSES];
    __shared__ int s_off[NUM_CLASSES];
    __shared__ int s_C;

    if (tid == 0) s_C = 0;
    if (tid < NUM_CLASSES) s_cnt[tid] = 0;

    // zero this batch's output rows (d_out is poisoned before every replay)
    for (int i = tid; i < DET_MAX * 6; i += 256)
        out[(size_t)b * DET_MAX * 6 + i] = 0.0f;
    __syncthreads();

    // ---- compact candidates (score >= 0) into LDS ----
    for (int i = tid; i < N_ROIS; i += 256) {
        float sc = ws_score[b * N_ROIS + i];
        if (sc >= 0.0f) {
            int k = atomicAdd(&s_C, 1);
            s_csc[k] = sc;
            s_cidx[k] = (short)i;
            int c = ws_cls[b * N_ROIS + i];
            s_ccls[k] = (unsigned char)c;
            atomicAdd(&s_cnt[c], 1);
            float4 bb = ((const float4*)ws_box)[b * N_ROIS + i];
            s_cbox[k][0] = bb.x; s_cbox[k][1] = bb.y;
            s_cbox[k][2] = bb.z; s_cbox[k][3] = bb.w;
        }
    }
    __syncthreads();
    const int C = s_C;

    if (tid == 0) {      // class bucket offsets (81 adds, trivial)
        int acc = 0;
        for (int c = 0; c < NUM_CLASSES; ++c) { s_off[c] = acc; acc += s_cnt[c]; }
    }
    __syncthreads();

    // ---- rank-sort by (score desc, idx asc) + direct class-bucket scatter ----
    for (int k = tid; k < C; k += 256) {
        float sk = s_csc[k];
        int ik = s_cidx[k];
        int ck = s_ccls[k];
        int rank = 0, crank = 0;
        for (int j = 0; j < C; ++j) {   // broadcast LDS reads
            float sj = s_csc[j];
            int before = (sj > sk) | ((sj == sk) & (s_cidx[j] < ik));
            rank += before;
            crank += before & (s_ccls[j] == ck);
        }
        s_ssc[rank] = sk;
        s_scls[rank] = (unsigned char)ck;
        s_sbox[rank][0] = s_cbox[k][0];
        s_sbox[rank][1] = s_cbox[k][1];
        s_sbox[rank][2] = s_cbox[k][2];
        s_sbox[rank][3] = s_cbox[k][3];
        s_kept[rank] = 0;
        s_bucket[s_off[ck] + crank] = (short)rank;
    }
    __syncthreads();

    // ---- per-class greedy NMS, all classes in parallel ----
    if (tid >= 1 && tid < NUM_CLASSES) {
        const int off = s_off[tid];
        const int m = s_cnt[tid];
        int kept_cnt = 0;
        for (int a = 0; a < m; ++a) {
            if (kept_cnt >= DET_MAX) break;
            int i = s_bucket[off + a];
            float b0 = s_sbox[i][0], b1 = s_sbox[i][1];
            float b2 = s_sbox[i][2], b3 = s_sbox[i][3];
            float area_b = (b2 - b0) * (b3 - b1);
            bool sup = false;
            for (int q = 0; q < a; ++q) {
                int j = s_bucket[off + q];
                if (!s_kept[j]) continue;
                float a0 = s_sbox[j][0], a1 = s_sbox[j][1];
                float a2 = s_sbox[j][2], a3 = s_sbox[j][3];
                float yy1 = fmaxf(a0, b0);
                float xx1 = fmaxf(a1, b1);
                float yy2 = fminf(a2, b2);
                float xx2 = fminf(a3, b3);
                float inter = fmaxf(yy2 - yy1, 0.0f) * fmaxf(xx2 - xx1, 0.0f);
                float area_a = (a2 - a0) * (a3 - a1);
                float uni = area_a + area_b - inter;
                if (inter / fmaxf(uni, 1e-10f) > NMS_THRESH) { sup = true; break; }
            }
            if (!sup) { s_kept[i] = 1; ++kept_cnt; }
        }
    }
    __syncthreads();

    // ---- emit: slot = prefix count of kept in sorted order (== top_k order) ----
    for (int i = tid; i < C; i += 256) {
        if (s_kept[i]) {
            int slot = 0;
            for (int j = 0; j < i; ++j) slot += s_kept[j];
            if (slot < DET_MAX) {
                float* o = out + (size_t)b * DET_MAX * 6 + slot * 6;
                o[0] = s_sbox[i][0];
                o[1] = s_sbox[i][1];
                o[2] = s_sbox[i][2];
                o[3] = s_sbox[i][3];
                o[4] = (float)s_scls[i];
                o[5] = s_ssc[i];
            }
        }
    }
}

extern "C" void kernel_launch(void* const* d_in, const int* in_sizes, int n_in,
                              void* d_out, int out_size, void* d_ws, size_t ws_size,
                              hipStream_t stream) {
    const float* rois      = (const float*)d_in[0];
    const float* fpn_class = (const float*)d_in[1];
    const float* fpn_bbox  = (const float*)d_in[2];
    const float* window    = (const float*)d_in[3];
    float* out = (float*)d_out;

    // workspace layout: boxes | scores | class ids  (384 KB of d_ws)
    float* ws_box   = (float*)d_ws;                        // BATCH*N_ROIS*4
    float* ws_score = ws_box + (size_t)BATCH * N_ROIS * 4; // BATCH*N_ROIS
    int*   ws_cls   = (int*)(ws_score + (size_t)BATCH * N_ROIS);

    refine_v4<<<BATCH * N_ROIS / ROI_TILE, 256, 0, stream>>>(
        rois, fpn_class, fpn_bbox, window, ws_box, ws_score, ws_cls);
    nms_v4<<<BATCH, 256, 0, stream>>>(ws_box, ws_score, ws_cls, out);
}